// Round 10
// baseline (320.638 us; speedup 1.0000x reference)
//
#include <hip/hip_runtime.h>

typedef _Float16 half8_t __attribute__((ext_vector_type(8)));
typedef __fp16   fp16x2_t __attribute__((ext_vector_type(2)));
typedef float    f32x4_t __attribute__((ext_vector_type(4)));
typedef unsigned int u32x4_t __attribute__((ext_vector_type(4)));

static constexpr int BATCH = 2048;
static constexpr int NSEQ  = BATCH * 64;   // 131072 sequences
static constexpr int VOCABN = 10000;
static constexpr float L2E = 1.44269504f;

__device__ __forceinline__ float sigm(float z) {
    float e = __builtin_amdgcn_exp2f(z * (-L2E));
    return __builtin_amdgcn_rcpf(1.f + e);
}
__device__ __forceinline__ float tanhp(float z) {
    float e = __builtin_amdgcn_exp2f(z * (2.f * L2E));
    return fmaf(-2.f, __builtin_amdgcn_rcpf(1.f + e), 1.f);
}

// ---------------------------------------------------------------------------
// Fused prep:
//  [0,5000)     zxt[v][row] = bias[row] + sum_d emb[v][d]*Wk[d][row]  (f32)
//  [5000,5008)  Wr A-fragments (sigma k-permutation, proven in R9)
//  [5008,5136)  Wd B-fragments for the projection GEMM
// ---------------------------------------------------------------------------
__global__ __launch_bounds__(256) void prep_all(const float* __restrict__ emb,
                                                const float* __restrict__ Wr,
                                                const float* __restrict__ Wk,
                                                const float* __restrict__ Wd,
                                                const float* __restrict__ bias,
                                                float* __restrict__ zxt,
                                                ushort* __restrict__ fwr,
                                                ushort* __restrict__ fwd) {
    const int bid = blockIdx.x, tid = threadIdx.x;
    if (bid < 5000) {                       // token pre-activation table
        const int v = bid * 2 + (tid >> 7);
        const int row = tid & 127;
        const float* er = emb + v * 32;     // uniform within each wave
        float a = bias[row];
        #pragma unroll
        for (int d = 0; d < 32; ++d) a = fmaf(er[d], Wk[d * 128 + row], a);
        zxt[v * 128 + row] = a;
    } else if (bid < 5008) {                // Wr A-fragments
        if (tid >= 64) return;
        const int lane = tid;
        const int b = bid - 5000;
        #pragma unroll
        for (int j = 0; j < 8; ++j) {
            int kk = (lane >> 4) * 8 + j;
            int krow = 4 * (kk >> 3) + (kk & 3) + 16 * ((kk >> 2) & 1);   // sigma
            int col = b * 16 + (lane & 15);
            _Float16 v = (_Float16)Wr[krow * 128 + col];
            fwr[(b * 64 + lane) * 8 + j] = __builtin_bit_cast(ushort, v);
        }
    } else {                                // Wd B-fragments (proj)
        const int idx = (bid - 5008) * 256 + tid;   // 0..32767
        const int lane = idx & 63, ksblk = idx >> 6;
        const int ks = ksblk >> 2, blk = ksblk & 3;
        #pragma unroll
        for (int j = 0; j < 8; ++j) {
            const int k = ks * 32 + (lane >> 4) * 8 + j;
            const int col = blk * 16 + (lane & 15);
            _Float16 v = (_Float16)Wd[k * 64 + col];
            fwd[ksblk * 512 + lane * 8 + j] = __builtin_bit_cast(ushort, v);
        }
    }
}

// ---------------------------------------------------------------------------
// Bidirectional LSTM, swapped-operand form with token-table C-operand:
// acc[b] = mfma(Awr[b], Bh, C = zxt[tok][b*16+4grp .. +3])  accumulates
// z = z_x(tok) + Wr^T @ h^T in one MFMA per block. No Wk MFMA, no bias regs,
// no LDS in the recurrence. B cols 0-7 = fw of 8 seqs, 8-15 = bw of same.
// D-layout: lane(i15,grp) reg r holds z[gate-row b*16+4grp+r][seq i15];
// packed gate outputs ARE next step's B-fragment (sigma baked into Wr frags).
// ---------------------------------------------------------------------------
__global__ __launch_bounds__(256) void lstm_mfma(const int* __restrict__ x,
                                                 const ushort* __restrict__ fwr,
                                                 const float* __restrict__ zxt,
                                                 ushort* __restrict__ state16) {
    __shared__ int toks[16 * 32];                // [t][seq-in-block]

    const int tid = threadIdx.x, lane = tid & 63, wid = tid >> 6;
    const int i15 = lane & 15, grp = lane >> 4;
    const long blkSeq = (long)blockIdx.x * 32;

    if (tid < 128) {   // stage 32 seqs x 16 tokens, transposed
        int s = tid >> 2, t4 = (tid & 3) * 4;
        int4 v = *(const int4*)(x + (blkSeq + s) * 16 + t4);
        toks[(t4 + 0) * 32 + s] = v.x; toks[(t4 + 1) * 32 + s] = v.y;
        toks[(t4 + 2) * 32 + s] = v.z; toks[(t4 + 3) * 32 + s] = v.w;
    }

    const half8_t* fwr8 = (const half8_t*)fwr;
    half8_t Awr[8];
    #pragma unroll
    for (int b = 0; b < 8; ++b) Awr[b] = fwr8[b * 64 + lane];

    __syncthreads();

    const int seqIB = wid * 8 + (i15 & 7);       // this lane's column's sequence
    const bool bw = i15 >= 8;                    // cols 8-15 run backward
    const int dstep = bw ? -32 : 32;
    int idx = (bw ? 15 * 32 : 0) + seqIB;

    float creg[4][2];                            // c for unit hf*16+4grp+r
    #pragma unroll
    for (int r = 0; r < 4; ++r) creg[r][0] = creg[r][1] = 0.f;
    half8_t Bh = __builtin_bit_cast(half8_t, (u32x4_t){0u, 0u, 0u, 0u});

    // prologue: tok(0), z_x(0) into zxc; advance idx to step 1
    int tok_cur = toks[idx];
    idx += dstep;
    f32x4_t zxc[8];
    {
        const float* zb = zxt + (long)tok_cur * 128 + grp * 4;
        #pragma unroll
        for (int b = 0; b < 8; ++b) zxc[b] = *(const f32x4_t*)(zb + b * 16);
    }

    f32x4_t acc[8];

    #pragma unroll 2
    for (int s = 0; s < 16; ++s) {
        // (A) single MFMA set: acc = z_x + Wr^T @ h^T   (C = zxc)
        #pragma unroll
        for (int b = 0; b < 8; ++b)
            acc[b] = __builtin_amdgcn_mfma_f32_16x16x32_f16(Awr[b], Bh, zxc[b], 0, 0, 0);
        // (B) prefetch z_x(s+1) into zxc (WAR on zxc: issued after the MFMAs)
        int tok_next = 0;
        if (s < 15) {
            tok_next = toks[idx];
            idx += dstep;
            const float* zb = zxt + (long)tok_next * 128 + grp * 4;
            #pragma unroll
            for (int b = 0; b < 8; ++b) zxc[b] = *(const f32x4_t*)(zb + b * 16);
        }
        // (C) gates + h/c update (all values of this lane belong to seq i15)
        const bool m = (tok_cur != 0);
        float hn[4][2];
        #pragma unroll
        for (int r = 0; r < 4; ++r) {
            #pragma unroll
            for (int hf = 0; hf < 2; ++hf) {
                float zi = acc[0 + hf][r], zf = acc[2 + hf][r];
                float zg = acc[4 + hf][r], zo = acc[6 + hf][r];
                float ii = sigm(zi);
                float ff = sigm(zf);
                float gg = tanhp(zg);
                float oo = sigm(zo);
                float cn = fmaf(ff, creg[r][hf], ii * gg);
                hn[r][hf] = oo * tanhp(cn);
                creg[r][hf] = m ? cn : creg[r][hf];
            }
        }
        // pack new h into next B-fragment (j = hf*4 + r ordering)
        fp16x2_t p0 = __builtin_amdgcn_cvt_pkrtz(hn[0][0], hn[1][0]);
        fp16x2_t p1 = __builtin_amdgcn_cvt_pkrtz(hn[2][0], hn[3][0]);
        fp16x2_t p2 = __builtin_amdgcn_cvt_pkrtz(hn[0][1], hn[1][1]);
        fp16x2_t p3 = __builtin_amdgcn_cvt_pkrtz(hn[2][1], hn[3][1]);
        u32x4_t w;
        w.x = __builtin_bit_cast(unsigned int, p0);
        w.y = __builtin_bit_cast(unsigned int, p1);
        w.z = __builtin_bit_cast(unsigned int, p2);
        w.w = __builtin_bit_cast(unsigned int, p3);
        half8_t Bh_new = __builtin_bit_cast(half8_t, w);
        Bh = m ? Bh_new : Bh;                    // packed select
        tok_cur = tok_next;
    }

    // epilogue: Bh words 0,1 = units 4grp..4grp+3 ; words 2,3 = 16+4grp..+3
    {
        u32x4_t wv = __builtin_bit_cast(u32x4_t, Bh);
        ushort* base = state16 + (blkSeq + seqIB) * 64 + (bw ? 32 : 0);
        uint2 lo = {wv.x, wv.y}, hi = {wv.z, wv.w};
        *(uint2*)(base + 4 * grp) = lo;
        *(uint2*)(base + 16 + 4 * grp) = hi;
    }
}

// ---------------------------------------------------------------------------
// Projection as MFMA GEMM (R5/R9-proven, verbatim):
// out[2048][64] = tanh(state16[2048][4096] @ Wd + bd).
// One wave per 16 batch rows; K=4096 in 128 steps of 32; bias via C-init.
// ---------------------------------------------------------------------------
__global__ __launch_bounds__(64) void proj_mfma(const ushort* __restrict__ state16,
                                                const ushort* __restrict__ fwd,
                                                const float* __restrict__ bd,
                                                float* __restrict__ out) {
    const int lane = threadIdx.x;
    const int i15 = lane & 15, grp = lane >> 4;
    const int r0 = blockIdx.x * 16;

    const half8_t* fw8 = (const half8_t*)fwd;
    const half8_t* sa  = (const half8_t*)state16;

    f32x4_t acc[4];
    #pragma unroll
    for (int blk = 0; blk < 4; ++blk) {
        float c = bd[blk * 16 + i15];
        acc[blk] = (f32x4_t){c, c, c, c};
    }

    const int abase = (r0 + i15) * 512 + grp;   // half8 index into state16
    #pragma unroll 4
    for (int ks = 0; ks < 128; ++ks) {
        half8_t A = sa[abase + ks * 4];
        #pragma unroll
        for (int blk = 0; blk < 4; ++blk)
            acc[blk] = __builtin_amdgcn_mfma_f32_16x16x32_f16(A, fw8[(ks * 4 + blk) * 64 + lane],
                                                              acc[blk], 0, 0, 0);
    }

    #pragma unroll
    for (int blk = 0; blk < 4; ++blk)
        #pragma unroll
        for (int q = 0; q < 4; ++q) {
            float e = __builtin_amdgcn_exp2f(acc[blk][q] * (2.f * L2E));
            float t = fmaf(-2.f, __builtin_amdgcn_rcpf(1.f + e), 1.f);
            out[(r0 + grp * 4 + q) * 64 + blk * 16 + i15] = t;
        }
}

extern "C" void kernel_launch(void* const* d_in, const int* in_sizes, int n_in,
                              void* d_out, int out_size, void* d_ws, size_t ws_size,
                              hipStream_t stream) {
    const int*   x    = (const int*)d_in[0];
    const float* emb  = (const float*)d_in[1];
    const float* Wk   = (const float*)d_in[2];
    const float* Wr   = (const float*)d_in[3];
    const float* bias = (const float*)d_in[4];
    const float* Wd   = (const float*)d_in[5];
    const float* bd   = (const float*)d_in[6];
    float* out = (float*)d_out;

    ushort* state16 = (ushort*)d_ws;                          // 16,777,216 B
    float*  zxt     = (float*)((char*)d_ws + 16777216);       //  5,120,000 B
    ushort* fwr     = (ushort*)((char*)d_ws + 21897216);      //      8,192 B
    ushort* fwd     = (ushort*)((char*)d_ws + 21905408);      //    524,288 B

    prep_all<<<5136, 256, 0, stream>>>(emb, Wr, Wk, Wd, bias, zxt, fwr, fwd);
    lstm_mfma<<<NSEQ / 32, 256, 0, stream>>>(x, fwr, zxt, state16);
    proj_mfma<<<BATCH / 16, 64, 0, stream>>>(state16, fwd, bd, out);
}

// Round 11
// 225.848 us; speedup vs baseline: 1.4197x; 1.4197x over previous
//
#include <hip/hip_runtime.h>

typedef _Float16 half8_t __attribute__((ext_vector_type(8)));
typedef __fp16   fp16x2_t __attribute__((ext_vector_type(2)));
typedef float    f32x4_t __attribute__((ext_vector_type(4)));
typedef unsigned int u32x4_t __attribute__((ext_vector_type(4)));

static constexpr int BATCH = 2048;
static constexpr int NSEQ  = BATCH * 64;   // 131072 sequences
static constexpr int VOCABN = 10000;
static constexpr float L2E = 1.44269504f;

// prescaled forms: acc rows already carry -L2E (i,f,o) or +2*L2E (g)
__device__ __forceinline__ float sig_pre(float zs) {
    float e = __builtin_amdgcn_exp2f(zs);
    return __builtin_amdgcn_rcpf(1.f + e);
}
__device__ __forceinline__ float tanh_pre(float zs) {
    float e = __builtin_amdgcn_exp2f(zs);
    return fmaf(-2.f, __builtin_amdgcn_rcpf(1.f + e), 1.f);
}
__device__ __forceinline__ float tanh_raw(float c) {
    float e = __builtin_amdgcn_exp2f(c * (2.f * L2E));
    return fmaf(-2.f, __builtin_amdgcn_rcpf(1.f + e), 1.f);
}

// ---------------------------------------------------------------------------
// Fused prep:
//  [0,5000)    zxt16[v][grp*32+b*4+r] = f16( s_row * (bias[row] + emb[v]@Wk[:,row]) )
//              row = b*16 + 4*grp + r ; s_row = +2*L2E for g-rows (b=4,5), else -L2E.
//              Per-grp-contiguous layout -> each lane reads 64 B contiguous.
//  [5000,5008) Wr A-fragments: sigma k-permutation (R9-proven) x same row scale.
//  [5008,5136) Wd B-fragments for the projection GEMM (R5-proven).
// ---------------------------------------------------------------------------
__global__ __launch_bounds__(256) void prep_all(const float* __restrict__ emb,
                                                const float* __restrict__ Wr,
                                                const float* __restrict__ Wk,
                                                const float* __restrict__ Wd,
                                                const float* __restrict__ bias,
                                                ushort* __restrict__ zxt16,
                                                ushort* __restrict__ fwr,
                                                ushort* __restrict__ fwd) {
    const int bid = blockIdx.x, tid = threadIdx.x;
    if (bid < 5000) {                       // token pre-activation table (f16)
        const int v = bid * 2 + (tid >> 7);
        const int row = tid & 127;
        const int b = row >> 4, grp = (row & 15) >> 2, r = row & 3;
        const float* er = emb + v * 32;     // uniform within each half-wave
        float a = bias[row];
        #pragma unroll
        for (int d = 0; d < 32; ++d) a = fmaf(er[d], Wk[d * 128 + row], a);
        const float s = (b == 4 || b == 5) ? (2.f * L2E) : (-L2E);
        _Float16 hv = (_Float16)(a * s);
        zxt16[v * 128 + grp * 32 + b * 4 + r] = __builtin_bit_cast(ushort, hv);
    } else if (bid < 5008) {                // Wr A-fragments (scaled)
        if (tid >= 64) return;
        const int lane = tid;
        const int b = bid - 5000;
        const float s = (b == 4 || b == 5) ? (2.f * L2E) : (-L2E);
        #pragma unroll
        for (int j = 0; j < 8; ++j) {
            int kk = (lane >> 4) * 8 + j;
            int krow = 4 * (kk >> 3) + (kk & 3) + 16 * ((kk >> 2) & 1);   // sigma
            int col = b * 16 + (lane & 15);
            _Float16 v = (_Float16)(Wr[krow * 128 + col] * s);
            fwr[(b * 64 + lane) * 8 + j] = __builtin_bit_cast(ushort, v);
        }
    } else {                                // Wd B-fragments (proj)
        const int idx = (bid - 5008) * 256 + tid;   // 0..32767
        const int lane = idx & 63, ksblk = idx >> 6;
        const int ks = ksblk >> 2, blk = ksblk & 3;
        #pragma unroll
        for (int j = 0; j < 8; ++j) {
            const int k = ks * 32 + (lane >> 4) * 8 + j;
            const int col = blk * 16 + (lane & 15);
            _Float16 v = (_Float16)Wd[k * 64 + col];
            fwd[ksblk * 512 + lane * 8 + j] = __builtin_bit_cast(ushort, v);
        }
    }
}

// ---------------------------------------------------------------------------
// Bidirectional LSTM, swapped-operand form with f16 token-table C-operand:
// acc[b] = mfma(Awr[b](scaled), Bh, C=cvt(zx16[tok])) gives prescaled gate
// pre-activations; sigmoid/tanh need no pre-multiply. Table is 2.56 MB ->
// L2-resident per XCD; each lane loads 64 B contiguous per step, double-
// buffered one step ahead. No LDS in the recurrence.
// ---------------------------------------------------------------------------
__global__ __launch_bounds__(256, 3) void lstm_mfma(const int* __restrict__ x,
                                                    const ushort* __restrict__ fwr,
                                                    const ushort* __restrict__ zxt16,
                                                    ushort* __restrict__ state16) {
    __shared__ int toks[16 * 32];                // [t][seq-in-block]

    const int tid = threadIdx.x, lane = tid & 63, wid = tid >> 6;
    const int i15 = lane & 15, grp = lane >> 4;
    const long blkSeq = (long)blockIdx.x * 32;

    if (tid < 128) {   // stage 32 seqs x 16 tokens, transposed
        int s = tid >> 2, t4 = (tid & 3) * 4;
        int4 v = *(const int4*)(x + (blkSeq + s) * 16 + t4);
        toks[(t4 + 0) * 32 + s] = v.x; toks[(t4 + 1) * 32 + s] = v.y;
        toks[(t4 + 2) * 32 + s] = v.z; toks[(t4 + 3) * 32 + s] = v.w;
    }

    const half8_t* fwr8 = (const half8_t*)fwr;
    half8_t Awr[8];
    #pragma unroll
    for (int b = 0; b < 8; ++b) Awr[b] = fwr8[b * 64 + lane];

    __syncthreads();

    const int seqIB = wid * 8 + (i15 & 7);       // this lane's column's sequence
    const bool bw = i15 >= 8;                    // cols 8-15 run backward
    const int dstep = bw ? -32 : 32;
    int idx = (bw ? 15 * 32 : 0) + seqIB;

    float creg[4][2];                            // c for unit hf*16+4grp+r
    #pragma unroll
    for (int r = 0; r < 4; ++r) creg[r][0] = creg[r][1] = 0.f;
    half8_t Bh = __builtin_bit_cast(half8_t, (u32x4_t){0u, 0u, 0u, 0u});

    // token pipeline (2 ahead) + zx double buffer (1 ahead)
    int tok_cur = toks[idx]; idx += dstep;
    int tok_nx  = toks[idx]; idx += dstep;
    const half8_t* ztab = (const half8_t*)zxt16;  // 16B units
    // lane's 64B slice = 4 half8 at (tok*128 + grp*32)/8 = tok*16 + grp*4
    half8_t zb0[4], zb1[4];
    {
        const half8_t* zr = ztab + (long)tok_cur * 16 + grp * 4;
        #pragma unroll
        for (int c = 0; c < 4; ++c) zb0[c] = zr[c];
    }

    f32x4_t acc[8];

    #pragma unroll 2
    for (int s = 0; s < 16; ++s) {
        // (A) cvt C + single MFMA set: acc = s_row*(z_x + Wr^T @ h^T)
        const half8_t* zc = (s & 1) ? zb1 : zb0;
        #pragma unroll
        for (int b = 0; b < 8; ++b) {
            const int c = b >> 1, o4 = (b & 1) * 4;
            f32x4_t cc = { (float)zc[c][o4 + 0], (float)zc[c][o4 + 1],
                           (float)zc[c][o4 + 2], (float)zc[c][o4 + 3] };
            acc[b] = __builtin_amdgcn_mfma_f32_16x16x32_f16(Awr[b], Bh, cc, 0, 0, 0);
        }
        // (B) prefetch zx(s+1) into the other parity buffer; tok 2 ahead
        if (s < 15) {
            const half8_t* zr = ztab + (long)tok_nx * 16 + grp * 4;
            if (s & 1) {
                #pragma unroll
                for (int c = 0; c < 4; ++c) zb0[c] = zr[c];
            } else {
                #pragma unroll
                for (int c = 0; c < 4; ++c) zb1[c] = zr[c];
            }
        }
        int tok_nn = 0;
        if (s < 14) { tok_nn = toks[idx]; idx += dstep; }
        // (C) gates + h/c update (all values of this lane belong to seq i15)
        const bool m = (tok_cur != 0);
        float hn[4][2];
        #pragma unroll
        for (int r = 0; r < 4; ++r) {
            #pragma unroll
            for (int hf = 0; hf < 2; ++hf) {
                float ii = sig_pre(acc[0 + hf][r]);
                float ff = sig_pre(acc[2 + hf][r]);
                float gg = tanh_pre(acc[4 + hf][r]);
                float oo = sig_pre(acc[6 + hf][r]);
                float cn = fmaf(ff, creg[r][hf], ii * gg);
                hn[r][hf] = oo * tanh_raw(cn);
                creg[r][hf] = m ? cn : creg[r][hf];
            }
        }
        // pack new h into next B-fragment (j = hf*4 + r ordering)
        fp16x2_t p0 = __builtin_amdgcn_cvt_pkrtz(hn[0][0], hn[1][0]);
        fp16x2_t p1 = __builtin_amdgcn_cvt_pkrtz(hn[2][0], hn[3][0]);
        fp16x2_t p2 = __builtin_amdgcn_cvt_pkrtz(hn[0][1], hn[1][1]);
        fp16x2_t p3 = __builtin_amdgcn_cvt_pkrtz(hn[2][1], hn[3][1]);
        u32x4_t w;
        w.x = __builtin_bit_cast(unsigned int, p0);
        w.y = __builtin_bit_cast(unsigned int, p1);
        w.z = __builtin_bit_cast(unsigned int, p2);
        w.w = __builtin_bit_cast(unsigned int, p3);
        half8_t Bh_new = __builtin_bit_cast(half8_t, w);
        Bh = m ? Bh_new : Bh;                    // packed select
        tok_cur = tok_nx; tok_nx = tok_nn;
    }

    // epilogue: Bh words 0,1 = units 4grp..4grp+3 ; words 2,3 = 16+4grp..+3
    {
        u32x4_t wv = __builtin_bit_cast(u32x4_t, Bh);
        ushort* base = state16 + (blkSeq + seqIB) * 64 + (bw ? 32 : 0);
        uint2 lo = {wv.x, wv.y}, hi = {wv.z, wv.w};
        *(uint2*)(base + 4 * grp) = lo;
        *(uint2*)(base + 16 + 4 * grp) = hi;
    }
}

// ---------------------------------------------------------------------------
// Projection as MFMA GEMM (R5/R9-proven, verbatim):
// out[2048][64] = tanh(state16[2048][4096] @ Wd + bd).
// ---------------------------------------------------------------------------
__global__ __launch_bounds__(64) void proj_mfma(const ushort* __restrict__ state16,
                                                const ushort* __restrict__ fwd,
                                                const float* __restrict__ bd,
                                                float* __restrict__ out) {
    const int lane = threadIdx.x;
    const int i15 = lane & 15, grp = lane >> 4;
    const int r0 = blockIdx.x * 16;

    const half8_t* fw8 = (const half8_t*)fwd;
    const half8_t* sa  = (const half8_t*)state16;

    f32x4_t acc[4];
    #pragma unroll
    for (int blk = 0; blk < 4; ++blk) {
        float c = bd[blk * 16 + i15];
        acc[blk] = (f32x4_t){c, c, c, c};
    }

    const int abase = (r0 + i15) * 512 + grp;   // half8 index into state16
    #pragma unroll 4
    for (int ks = 0; ks < 128; ++ks) {
        half8_t A = sa[abase + ks * 4];
        #pragma unroll
        for (int blk = 0; blk < 4; ++blk)
            acc[blk] = __builtin_amdgcn_mfma_f32_16x16x32_f16(A, fw8[(ks * 4 + blk) * 64 + lane],
                                                              acc[blk], 0, 0, 0);
    }

    #pragma unroll
    for (int blk = 0; blk < 4; ++blk)
        #pragma unroll
        for (int q = 0; q < 4; ++q) {
            float e = __builtin_amdgcn_exp2f(acc[blk][q] * (2.f * L2E));
            float t = fmaf(-2.f, __builtin_amdgcn_rcpf(1.f + e), 1.f);
            out[(r0 + grp * 4 + q) * 64 + blk * 16 + i15] = t;
        }
}

extern "C" void kernel_launch(void* const* d_in, const int* in_sizes, int n_in,
                              void* d_out, int out_size, void* d_ws, size_t ws_size,
                              hipStream_t stream) {
    const int*   x    = (const int*)d_in[0];
    const float* emb  = (const float*)d_in[1];
    const float* Wk   = (const float*)d_in[2];
    const float* Wr   = (const float*)d_in[3];
    const float* bias = (const float*)d_in[4];
    const float* Wd   = (const float*)d_in[5];
    const float* bd   = (const float*)d_in[6];
    float* out = (float*)d_out;

    ushort* state16 = (ushort*)d_ws;                          // 16,777,216 B
    ushort* zxt16   = (ushort*)((char*)d_ws + 16777216);      //  2,560,000 B
    ushort* fwr     = (ushort*)((char*)d_ws + 19337216);      //      8,192 B
    ushort* fwd     = (ushort*)((char*)d_ws + 19345408);      //    524,288 B

    prep_all<<<5136, 256, 0, stream>>>(emb, Wr, Wk, Wd, bias, zxt16, fwr, fwd);
    lstm_mfma<<<NSEQ / 32, 256, 0, stream>>>(x, fwr, zxt16, state16);
    proj_mfma<<<BATCH / 16, 64, 0, stream>>>(state16, fwd, bd, out);
}

// Round 12
// 182.441 us; speedup vs baseline: 1.7575x; 1.2379x over previous
//
#include <hip/hip_runtime.h>

typedef _Float16 half8_t __attribute__((ext_vector_type(8)));
typedef __fp16   fp16x2_t __attribute__((ext_vector_type(2)));
typedef float    f32x4_t __attribute__((ext_vector_type(4)));
typedef unsigned int u32x4_t __attribute__((ext_vector_type(4)));

static constexpr int BATCH = 2048;
static constexpr int NSEQ  = BATCH * 64;   // 131072 sequences
static constexpr int VOCABN = 10000;
static constexpr float L2E = 1.44269504f;

// ---------------------------------------------------------------------------
// Fused prep (verbatim R11-proven):
//  [0,5000)    zxt16[v][grp*32+b*4+r] = f16( s_row * (bias[row] + emb[v]@Wk[:,row]) )
//              row = b*16+4*grp+r ; s_row = +2*L2E for g-rows (b=4,5) else -L2E.
//  [5000,5008) Wr A-fragments: sigma k-permutation x same row scale.
//  [5008,5136) Wd B-fragments for the projection GEMM.
// ---------------------------------------------------------------------------
__global__ __launch_bounds__(256) void prep_all(const float* __restrict__ emb,
                                                const float* __restrict__ Wr,
                                                const float* __restrict__ Wk,
                                                const float* __restrict__ Wd,
                                                const float* __restrict__ bias,
                                                ushort* __restrict__ zxt16,
                                                ushort* __restrict__ fwr,
                                                ushort* __restrict__ fwd) {
    const int bid = blockIdx.x, tid = threadIdx.x;
    if (bid < 5000) {                       // token pre-activation table (f16)
        const int v = bid * 2 + (tid >> 7);
        const int row = tid & 127;
        const int b = row >> 4, grp = (row & 15) >> 2, r = row & 3;
        const float* er = emb + v * 32;     // uniform within each half-block
        float a = bias[row];
        #pragma unroll
        for (int d = 0; d < 32; ++d) a = fmaf(er[d], Wk[d * 128 + row], a);
        const float s = (b == 4 || b == 5) ? (2.f * L2E) : (-L2E);
        _Float16 hv = (_Float16)(a * s);
        zxt16[v * 128 + grp * 32 + b * 4 + r] = __builtin_bit_cast(ushort, hv);
    } else if (bid < 5008) {                // Wr A-fragments (scaled)
        if (tid >= 64) return;
        const int lane = tid;
        const int b = bid - 5000;
        const float s = (b == 4 || b == 5) ? (2.f * L2E) : (-L2E);
        #pragma unroll
        for (int j = 0; j < 8; ++j) {
            int kk = (lane >> 4) * 8 + j;
            int krow = 4 * (kk >> 3) + (kk & 3) + 16 * ((kk >> 2) & 1);   // sigma
            int col = b * 16 + (lane & 15);
            _Float16 v = (_Float16)(Wr[krow * 128 + col] * s);
            fwr[(b * 64 + lane) * 8 + j] = __builtin_bit_cast(ushort, v);
        }
    } else {                                // Wd B-fragments (proj)
        const int idx = (bid - 5008) * 256 + tid;   // 0..32767
        const int lane = idx & 63, ksblk = idx >> 6;
        const int ks = ksblk >> 2, blk = ksblk & 3;
        #pragma unroll
        for (int j = 0; j < 8; ++j) {
            const int k = ks * 32 + (lane >> 4) * 8 + j;
            const int col = blk * 16 + (lane & 15);
            _Float16 v = (_Float16)Wd[k * 64 + col];
            fwd[ksblk * 512 + lane * 8 + j] = __builtin_bit_cast(ushort, v);
        }
    }
}

// ---------------------------------------------------------------------------
// Bidirectional LSTM (R11 structure + rational-form gates: 8 trans/unit).
// acc rows are prescaled: i,f,o rows by -L2E, g rows by +2*L2E, so
// Ei=e^{-zi}, Eg=e^{2zg} etc.  Then:
//   f*c        = c * rcp(1+Ef)
//   i*g        = (Eg-1) * rcp((1+Ei)(1+Eg))
//   o*tanh(c') = (Ec-1) * rcp((1+Eo)(1+Ec)),  Ec = exp2(2*L2E*c')
// ---------------------------------------------------------------------------
__global__ __launch_bounds__(256, 3) void lstm_mfma(const int* __restrict__ x,
                                                    const ushort* __restrict__ fwr,
                                                    const ushort* __restrict__ zxt16,
                                                    ushort* __restrict__ state16) {
    __shared__ int toks[16 * 32];                // [t][seq-in-block]

    const int tid = threadIdx.x, lane = tid & 63, wid = tid >> 6;
    const int i15 = lane & 15, grp = lane >> 4;
    const long blkSeq = (long)blockIdx.x * 32;

    if (tid < 128) {   // stage 32 seqs x 16 tokens, transposed
        int s = tid >> 2, t4 = (tid & 3) * 4;
        int4 v = *(const int4*)(x + (blkSeq + s) * 16 + t4);
        toks[(t4 + 0) * 32 + s] = v.x; toks[(t4 + 1) * 32 + s] = v.y;
        toks[(t4 + 2) * 32 + s] = v.z; toks[(t4 + 3) * 32 + s] = v.w;
    }

    const half8_t* fwr8 = (const half8_t*)fwr;
    half8_t Awr[8];
    #pragma unroll
    for (int b = 0; b < 8; ++b) Awr[b] = fwr8[b * 64 + lane];

    __syncthreads();

    const int seqIB = wid * 8 + (i15 & 7);       // this lane's column's sequence
    const bool bw = i15 >= 8;                    // cols 8-15 run backward
    const int dstep = bw ? -32 : 32;
    int idx = (bw ? 15 * 32 : 0) + seqIB;

    float creg[4][2];                            // c for unit hf*16+4grp+r
    #pragma unroll
    for (int r = 0; r < 4; ++r) creg[r][0] = creg[r][1] = 0.f;
    half8_t Bh = __builtin_bit_cast(half8_t, (u32x4_t){0u, 0u, 0u, 0u});

    // token pipeline (2 ahead) + zx double buffer (1 ahead)
    int tok_cur = toks[idx]; idx += dstep;
    int tok_nx  = toks[idx]; idx += dstep;
    const half8_t* ztab = (const half8_t*)zxt16;  // 16B units
    half8_t zb0[4], zb1[4];
    {
        const half8_t* zr = ztab + (long)tok_cur * 16 + grp * 4;
        #pragma unroll
        for (int c = 0; c < 4; ++c) zb0[c] = zr[c];
    }

    f32x4_t acc[8];

    #pragma unroll 2
    for (int s = 0; s < 16; ++s) {
        // (A) cvt C + single MFMA set: acc = s_row*(z_x + Wr^T @ h^T)
        const half8_t* zc = (s & 1) ? zb1 : zb0;
        #pragma unroll
        for (int b = 0; b < 8; ++b) {
            const int c = b >> 1, o4 = (b & 1) * 4;
            f32x4_t cc = { (float)zc[c][o4 + 0], (float)zc[c][o4 + 1],
                           (float)zc[c][o4 + 2], (float)zc[c][o4 + 3] };
            acc[b] = __builtin_amdgcn_mfma_f32_16x16x32_f16(Awr[b], Bh, cc, 0, 0, 0);
        }
        // (B) prefetch zx(s+1) into the other parity buffer; tok 2 ahead
        if (s < 15) {
            const half8_t* zr = ztab + (long)tok_nx * 16 + grp * 4;
            if (s & 1) {
                #pragma unroll
                for (int c = 0; c < 4; ++c) zb0[c] = zr[c];
            } else {
                #pragma unroll
                for (int c = 0; c < 4; ++c) zb1[c] = zr[c];
            }
        }
        int tok_nn = 0;
        if (s < 14) { tok_nn = toks[idx]; idx += dstep; }
        // (C) rational-form gates + h/c update
        const bool m = (tok_cur != 0);
        float hn[4][2];
        #pragma unroll
        for (int r = 0; r < 4; ++r) {
            #pragma unroll
            for (int hf = 0; hf < 2; ++hf) {
                float Ei = __builtin_amdgcn_exp2f(acc[0 + hf][r]);
                float Ef = __builtin_amdgcn_exp2f(acc[2 + hf][r]);
                float Eg = __builtin_amdgcn_exp2f(acc[4 + hf][r]);
                float Eo = __builtin_amdgcn_exp2f(acc[6 + hf][r]);
                float rf  = __builtin_amdgcn_rcpf(1.f + Ef);
                float rig = __builtin_amdgcn_rcpf((1.f + Ei) * (1.f + Eg));
                float cn  = fmaf(creg[r][hf], rf, (Eg - 1.f) * rig);
                float Ec  = __builtin_amdgcn_exp2f(cn * (2.f * L2E));
                float roc = __builtin_amdgcn_rcpf((1.f + Eo) * (1.f + Ec));
                hn[r][hf] = (Ec - 1.f) * roc;
                creg[r][hf] = m ? cn : creg[r][hf];
            }
        }
        // pack new h into next B-fragment (j = hf*4 + r ordering)
        fp16x2_t p0 = __builtin_amdgcn_cvt_pkrtz(hn[0][0], hn[1][0]);
        fp16x2_t p1 = __builtin_amdgcn_cvt_pkrtz(hn[2][0], hn[3][0]);
        fp16x2_t p2 = __builtin_amdgcn_cvt_pkrtz(hn[0][1], hn[1][1]);
        fp16x2_t p3 = __builtin_amdgcn_cvt_pkrtz(hn[2][1], hn[3][1]);
        u32x4_t w;
        w.x = __builtin_bit_cast(unsigned int, p0);
        w.y = __builtin_bit_cast(unsigned int, p1);
        w.z = __builtin_bit_cast(unsigned int, p2);
        w.w = __builtin_bit_cast(unsigned int, p3);
        half8_t Bh_new = __builtin_bit_cast(half8_t, w);
        Bh = m ? Bh_new : Bh;                    // packed select
        tok_cur = tok_nx; tok_nx = tok_nn;
    }

    // epilogue: Bh words 0,1 = units 4grp..4grp+3 ; words 2,3 = 16+4grp..+3
    {
        u32x4_t wv = __builtin_bit_cast(u32x4_t, Bh);
        ushort* base = state16 + (blkSeq + seqIB) * 64 + (bw ? 32 : 0);
        uint2 lo = {wv.x, wv.y}, hi = {wv.z, wv.w};
        *(uint2*)(base + 4 * grp) = lo;
        *(uint2*)(base + 16 + 4 * grp) = hi;
    }
}

// ---------------------------------------------------------------------------
// Projection GEMM: out[2048][64] = tanh(state16[2048][4096] @ Wd + bd).
// R5-proven math with blk := wid — 4 waves/block, each wave owns one 16-col
// N-block. No inter-wave communication, no LDS, no reduce.
// ---------------------------------------------------------------------------
__global__ __launch_bounds__(256) void proj_mfma(const ushort* __restrict__ state16,
                                                 const ushort* __restrict__ fwd,
                                                 const float* __restrict__ bd,
                                                 float* __restrict__ out) {
    const int tid = threadIdx.x, lane = tid & 63, wid = tid >> 6;
    const int i15 = lane & 15, grp = lane >> 4;
    const int r0 = blockIdx.x * 16;

    const half8_t* fw8 = (const half8_t*)fwd;
    const half8_t* sa  = (const half8_t*)state16;

    float cinit = bd[wid * 16 + i15];
    f32x4_t acc = {cinit, cinit, cinit, cinit};

    const int abase = (r0 + i15) * 512 + grp;   // half8 index into state16
    #pragma unroll 4
    for (int ks = 0; ks < 128; ++ks) {
        half8_t A = sa[abase + ks * 4];
        acc = __builtin_amdgcn_mfma_f32_16x16x32_f16(A, fw8[(ks * 4 + wid) * 64 + lane],
                                                     acc, 0, 0, 0);
    }

    #pragma unroll
    for (int q = 0; q < 4; ++q) {
        float e = __builtin_amdgcn_exp2f(acc[q] * (2.f * L2E));
        float t = fmaf(-2.f, __builtin_amdgcn_rcpf(1.f + e), 1.f);
        out[(r0 + grp * 4 + q) * 64 + wid * 16 + i15] = t;
    }
}

extern "C" void kernel_launch(void* const* d_in, const int* in_sizes, int n_in,
                              void* d_out, int out_size, void* d_ws, size_t ws_size,
                              hipStream_t stream) {
    const int*   x    = (const int*)d_in[0];
    const float* emb  = (const float*)d_in[1];
    const float* Wk   = (const float*)d_in[2];
    const float* Wr   = (const float*)d_in[3];
    const float* bias = (const float*)d_in[4];
    const float* Wd   = (const float*)d_in[5];
    const float* bd   = (const float*)d_in[6];
    float* out = (float*)d_out;

    ushort* state16 = (ushort*)d_ws;                          // 16,777,216 B
    ushort* zxt16   = (ushort*)((char*)d_ws + 16777216);      //  2,560,000 B
    ushort* fwr     = (ushort*)((char*)d_ws + 19337216);      //      8,192 B
    ushort* fwd     = (ushort*)((char*)d_ws + 19345408);      //    524,288 B

    prep_all<<<5136, 256, 0, stream>>>(emb, Wr, Wk, Wd, bias, zxt16, fwr, fwd);
    lstm_mfma<<<NSEQ / 32, 256, 0, stream>>>(x, fwr, zxt16, state16);
    proj_mfma<<<BATCH / 16, 256, 0, stream>>>(state16, fwd, bd, out);
}

// Round 13
// 178.559 us; speedup vs baseline: 1.7957x; 1.0217x over previous
//
#include <hip/hip_runtime.h>

typedef _Float16 half8_t __attribute__((ext_vector_type(8)));
typedef __fp16   fp16x2_t __attribute__((ext_vector_type(2)));
typedef float    f32x4_t __attribute__((ext_vector_type(4)));
typedef unsigned int u32x4_t __attribute__((ext_vector_type(4)));

static constexpr int BATCH = 2048;
static constexpr int NSEQ  = BATCH * 64;   // 131072 sequences
static constexpr int VOCABN = 10000;
static constexpr float L2E = 1.44269504f;

// ---------------------------------------------------------------------------
// Fused prep (R11/R12-proven, verbatim):
//  [0,5000)    zxt16[v][grp*32+b*4+r] = f16( s_row * (bias[row] + emb[v]@Wk[:,row]) )
//              row = b*16+4*grp+r ; s_row = +2*L2E for g-rows (b=4,5) else -L2E.
//  [5000,5008) Wr A-fragments: sigma k-permutation x same row scale.
//  [5008,5136) Wd B-fragments for the projection GEMM.
// ---------------------------------------------------------------------------
__global__ __launch_bounds__(256) void prep_all(const float* __restrict__ emb,
                                                const float* __restrict__ Wr,
                                                const float* __restrict__ Wk,
                                                const float* __restrict__ Wd,
                                                const float* __restrict__ bias,
                                                ushort* __restrict__ zxt16,
                                                ushort* __restrict__ fwr,
                                                ushort* __restrict__ fwd) {
    const int bid = blockIdx.x, tid = threadIdx.x;
    if (bid < 5000) {                       // token pre-activation table (f16)
        const int v = bid * 2 + (tid >> 7);
        const int row = tid & 127;
        const int b = row >> 4, grp = (row & 15) >> 2, r = row & 3;
        const float* er = emb + v * 32;     // uniform within each half-block
        float a = bias[row];
        #pragma unroll
        for (int d = 0; d < 32; ++d) a = fmaf(er[d], Wk[d * 128 + row], a);
        const float s = (b == 4 || b == 5) ? (2.f * L2E) : (-L2E);
        _Float16 hv = (_Float16)(a * s);
        zxt16[v * 128 + grp * 32 + b * 4 + r] = __builtin_bit_cast(ushort, hv);
    } else if (bid < 5008) {                // Wr A-fragments (scaled)
        if (tid >= 64) return;
        const int lane = tid;
        const int b = bid - 5000;
        const float s = (b == 4 || b == 5) ? (2.f * L2E) : (-L2E);
        #pragma unroll
        for (int j = 0; j < 8; ++j) {
            int kk = (lane >> 4) * 8 + j;
            int krow = 4 * (kk >> 3) + (kk & 3) + 16 * ((kk >> 2) & 1);   // sigma
            int col = b * 16 + (lane & 15);
            _Float16 v = (_Float16)(Wr[krow * 128 + col] * s);
            fwr[(b * 64 + lane) * 8 + j] = __builtin_bit_cast(ushort, v);
        }
    } else {                                // Wd B-fragments (proj)
        const int idx = (bid - 5008) * 256 + tid;   // 0..32767
        const int lane = idx & 63, ksblk = idx >> 6;
        const int ks = ksblk >> 2, blk = ksblk & 3;
        #pragma unroll
        for (int j = 0; j < 8; ++j) {
            const int k = ks * 32 + (lane >> 4) * 8 + j;
            const int col = blk * 16 + (lane & 15);
            _Float16 v = (_Float16)Wd[k * 64 + col];
            fwd[ksblk * 512 + lane * 8 + j] = __builtin_bit_cast(ushort, v);
        }
    }
}

// ---------------------------------------------------------------------------
// Bidirectional LSTM (R12 structure + 7-trans gates + reg trim).
// acc rows prescaled: i,f,o by -L2E, g by +2*L2E, so Ei=e^{-zi}, Eg=e^{2zg}.
//   cn = [c*D2 + (Eg-1)*D1] * rcp(D1*D2),  D1 = 1+Ef, D2 = (1+Ei)(1+Eg)
//   h  = (Ec-1) * rcp((1+Eo)(1+Ec)),       Ec = exp2(2*L2E*cn)
// 5 exp2 + 2 rcp per unit (exact algebra).
// ---------------------------------------------------------------------------
__global__ __launch_bounds__(256, 3) void lstm_mfma(const int* __restrict__ x,
                                                    const ushort* __restrict__ fwr,
                                                    const ushort* __restrict__ zxt16,
                                                    ushort* __restrict__ state16) {
    __shared__ int toks[16 * 32];                // [t][seq-in-block]

    const int tid = threadIdx.x, lane = tid & 63, wid = tid >> 6;
    const int i15 = lane & 15, grp = lane >> 4;
    const long blkSeq = (long)blockIdx.x * 32;

    if (tid < 128) {   // stage 32 seqs x 16 tokens, transposed
        int s = tid >> 2, t4 = (tid & 3) * 4;
        int4 v = *(const int4*)(x + (blkSeq + s) * 16 + t4);
        toks[(t4 + 0) * 32 + s] = v.x; toks[(t4 + 1) * 32 + s] = v.y;
        toks[(t4 + 2) * 32 + s] = v.z; toks[(t4 + 3) * 32 + s] = v.w;
    }

    const half8_t* fwr8 = (const half8_t*)fwr;
    half8_t Awr[8];
    #pragma unroll
    for (int b = 0; b < 8; ++b) Awr[b] = fwr8[b * 64 + lane];

    __syncthreads();

    const int seqIB = wid * 8 + (i15 & 7);       // this lane's column's sequence
    const bool bw = i15 >= 8;                    // cols 8-15 run backward
    const int dstep = bw ? -32 : 32;
    int idx = (bw ? 15 * 32 : 0) + seqIB;

    float creg[4][2];                            // c for unit hf*16+4grp+r
    #pragma unroll
    for (int r = 0; r < 4; ++r) creg[r][0] = creg[r][1] = 0.f;
    half8_t Bh = __builtin_bit_cast(half8_t, (u32x4_t){0u, 0u, 0u, 0u});

    // token pipeline (1 ahead) + zx double buffer (1 ahead)
    int tok_cur = toks[idx]; idx += dstep;
    int tok_nx  = toks[idx]; idx += dstep;
    const half8_t* ztab = (const half8_t*)zxt16;  // 16B units
    half8_t zb0[4], zb1[4];
    {
        const half8_t* zr = ztab + (long)tok_cur * 16 + grp * 4;
        #pragma unroll
        for (int c = 0; c < 4; ++c) zb0[c] = zr[c];
    }

    f32x4_t acc[8];

    #pragma unroll 2
    for (int s = 0; s < 16; ++s) {
        // (A) cvt C + single MFMA set: acc = s_row*(z_x + Wr^T @ h^T)
        const half8_t* zc = (s & 1) ? zb1 : zb0;
        #pragma unroll
        for (int b = 0; b < 8; ++b) {
            const int c = b >> 1, o4 = (b & 1) * 4;
            f32x4_t cc = { (float)zc[c][o4 + 0], (float)zc[c][o4 + 1],
                           (float)zc[c][o4 + 2], (float)zc[c][o4 + 3] };
            acc[b] = __builtin_amdgcn_mfma_f32_16x16x32_f16(Awr[b], Bh, cc, 0, 0, 0);
        }
        // (B) prefetch zx(s+1) into the other parity buffer
        if (s < 15) {
            const half8_t* zr = ztab + (long)tok_nx * 16 + grp * 4;
            if (s & 1) {
                #pragma unroll
                for (int c = 0; c < 4; ++c) zb0[c] = zr[c];
            } else {
                #pragma unroll
                for (int c = 0; c < 4; ++c) zb1[c] = zr[c];
            }
        }
        // (C) 7-trans rational gates + h/c update; pack per-hf immediately
        const bool m = (tok_cur != 0);
        u32x4_t w;
        #pragma unroll
        for (int hf = 0; hf < 2; ++hf) {
            float hn[4];
            #pragma unroll
            for (int r = 0; r < 4; ++r) {
                float Ei = __builtin_amdgcn_exp2f(acc[0 + hf][r]);
                float Ef = __builtin_amdgcn_exp2f(acc[2 + hf][r]);
                float Eg = __builtin_amdgcn_exp2f(acc[4 + hf][r]);
                float Eo = __builtin_amdgcn_exp2f(acc[6 + hf][r]);
                float D1 = 1.f + Ef;
                float D2 = (1.f + Ei) * (1.f + Eg);
                float num = fmaf(creg[r][hf], D2, (Eg - 1.f) * D1);
                float cn  = num * __builtin_amdgcn_rcpf(D1 * D2);
                float Ec  = __builtin_amdgcn_exp2f(cn * (2.f * L2E));
                float roc = __builtin_amdgcn_rcpf((1.f + Eo) * (1.f + Ec));
                hn[r] = (Ec - 1.f) * roc;
                creg[r][hf] = m ? cn : creg[r][hf];
            }
            fp16x2_t pa = __builtin_amdgcn_cvt_pkrtz(hn[0], hn[1]);
            fp16x2_t pb = __builtin_amdgcn_cvt_pkrtz(hn[2], hn[3]);
            if (hf == 0) { w.x = __builtin_bit_cast(unsigned int, pa);
                           w.y = __builtin_bit_cast(unsigned int, pb); }
            else         { w.z = __builtin_bit_cast(unsigned int, pa);
                           w.w = __builtin_bit_cast(unsigned int, pb); }
        }
        half8_t Bh_new = __builtin_bit_cast(half8_t, w);
        Bh = m ? Bh_new : Bh;                    // packed select
        // advance token pipeline (LDS read hides under next step's MFMA/gates)
        tok_cur = tok_nx;
        if (s < 14) { tok_nx = toks[idx]; idx += dstep; }
    }

    // epilogue: Bh words 0,1 = units 4grp..4grp+3 ; words 2,3 = 16+4grp..+3
    {
        u32x4_t wv = __builtin_bit_cast(u32x4_t, Bh);
        ushort* base = state16 + (blkSeq + seqIB) * 64 + (bw ? 32 : 0);
        uint2 lo = {wv.x, wv.y}, hi = {wv.z, wv.w};
        *(uint2*)(base + 4 * grp) = lo;
        *(uint2*)(base + 16 + 4 * grp) = hi;
    }
}

// ---------------------------------------------------------------------------
// Projection GEMM (R12-proven, verbatim): 4 waves/block, wave = one 16-col
// N-block, no LDS/reduce. out = tanh(state16 @ Wd + bd).
// ---------------------------------------------------------------------------
__global__ __launch_bounds__(256) void proj_mfma(const ushort* __restrict__ state16,
                                                 const ushort* __restrict__ fwd,
                                                 const float* __restrict__ bd,
                                                 float* __restrict__ out) {
    const int tid = threadIdx.x, lane = tid & 63, wid = tid >> 6;
    const int i15 = lane & 15, grp = lane >> 4;
    const int r0 = blockIdx.x * 16;

    const half8_t* fw8 = (const half8_t*)fwd;
    const half8_t* sa  = (const half8_t*)state16;

    float cinit = bd[wid * 16 + i15];
    f32x4_t acc = {cinit, cinit, cinit, cinit};

    const int abase = (r0 + i15) * 512 + grp;   // half8 index into state16
    #pragma unroll 4
    for (int ks = 0; ks < 128; ++ks) {
        half8_t A = sa[abase + ks * 4];
        acc = __builtin_amdgcn_mfma_f32_16x16x32_f16(A, fw8[(ks * 4 + wid) * 64 + lane],
                                                     acc, 0, 0, 0);
    }

    #pragma unroll
    for (int q = 0; q < 4; ++q) {
        float e = __builtin_amdgcn_exp2f(acc[q] * (2.f * L2E));
        float t = fmaf(-2.f, __builtin_amdgcn_rcpf(1.f + e), 1.f);
        out[(r0 + grp * 4 + q) * 64 + wid * 16 + i15] = t;
    }
}

extern "C" void kernel_launch(void* const* d_in, const int* in_sizes, int n_in,
                              void* d_out, int out_size, void* d_ws, size_t ws_size,
                              hipStream_t stream) {
    const int*   x    = (const int*)d_in[0];
    const float* emb  = (const float*)d_in[1];
    const float* Wk   = (const float*)d_in[2];
    const float* Wr   = (const float*)d_in[3];
    const float* bias = (const float*)d_in[4];
    const float* Wd   = (const float*)d_in[5];
    const float* bd   = (const float*)d_in[6];
    float* out = (float*)d_out;

    ushort* state16 = (ushort*)d_ws;                          // 16,777,216 B
    ushort* zxt16   = (ushort*)((char*)d_ws + 16777216);      //  2,560,000 B
    ushort* fwr     = (ushort*)((char*)d_ws + 19337216);      //      8,192 B
    ushort* fwd     = (ushort*)((char*)d_ws + 19345408);      //    524,288 B

    prep_all<<<5136, 256, 0, stream>>>(emb, Wr, Wk, Wd, bias, zxt16, fwr, fwd);
    lstm_mfma<<<NSEQ / 32, 256, 0, stream>>>(x, fwr, zxt16, state16);
    proj_mfma<<<BATCH / 16, 256, 0, stream>>>(state16, fwd, bd, out);
}

// Round 14
// 172.283 us; speedup vs baseline: 1.8611x; 1.0364x over previous
//
#include <hip/hip_runtime.h>

typedef _Float16 half8_t __attribute__((ext_vector_type(8)));
typedef __fp16   fp16x2_t __attribute__((ext_vector_type(2)));
typedef float    f32x4_t __attribute__((ext_vector_type(4)));
typedef unsigned int u32x4_t __attribute__((ext_vector_type(4)));

static constexpr int BATCH = 2048;
static constexpr int NSEQ  = BATCH * 64;   // 131072 sequences
static constexpr int VOCABN = 10000;
static constexpr float L2E = 1.44269504f;

// ---------------------------------------------------------------------------
// Fused prep (R11-R13 proven, verbatim):
//  [0,5000)    zxt16[v][grp*32+b*4+r] = f16( s_row * (bias[row] + emb[v]@Wk[:,row]) )
//              row = b*16+4*grp+r ; s_row = +2*L2E for g-rows (b=4,5) else -L2E.
//  [5000,5008) Wr A-fragments: sigma k-permutation x same row scale.
//  [5008,5136) Wd B-fragments for the projection GEMM.
// ---------------------------------------------------------------------------
__global__ __launch_bounds__(256) void prep_all(const float* __restrict__ emb,
                                                const float* __restrict__ Wr,
                                                const float* __restrict__ Wk,
                                                const float* __restrict__ Wd,
                                                const float* __restrict__ bias,
                                                ushort* __restrict__ zxt16,
                                                ushort* __restrict__ fwr,
                                                ushort* __restrict__ fwd) {
    const int bid = blockIdx.x, tid = threadIdx.x;
    if (bid < 5000) {                       // token pre-activation table (f16)
        const int v = bid * 2 + (tid >> 7);
        const int row = tid & 127;
        const int b = row >> 4, grp = (row & 15) >> 2, r = row & 3;
        const float* er = emb + v * 32;     // uniform within each half-block
        float a = bias[row];
        #pragma unroll
        for (int d = 0; d < 32; ++d) a = fmaf(er[d], Wk[d * 128 + row], a);
        const float s = (b == 4 || b == 5) ? (2.f * L2E) : (-L2E);
        _Float16 hv = (_Float16)(a * s);
        zxt16[v * 128 + grp * 32 + b * 4 + r] = __builtin_bit_cast(ushort, hv);
    } else if (bid < 5008) {                // Wr A-fragments (scaled)
        if (tid >= 64) return;
        const int lane = tid;
        const int b = bid - 5000;
        const float s = (b == 4 || b == 5) ? (2.f * L2E) : (-L2E);
        #pragma unroll
        for (int j = 0; j < 8; ++j) {
            int kk = (lane >> 4) * 8 + j;
            int krow = 4 * (kk >> 3) + (kk & 3) + 16 * ((kk >> 2) & 1);   // sigma
            int col = b * 16 + (lane & 15);
            _Float16 v = (_Float16)(Wr[krow * 128 + col] * s);
            fwr[(b * 64 + lane) * 8 + j] = __builtin_bit_cast(ushort, v);
        }
    } else {                                // Wd B-fragments (proj)
        const int idx = (bid - 5008) * 256 + tid;   // 0..32767
        const int lane = idx & 63, ksblk = idx >> 6;
        const int ks = ksblk >> 2, blk = ksblk & 3;
        #pragma unroll
        for (int j = 0; j < 8; ++j) {
            const int k = ks * 32 + (lane >> 4) * 8 + j;
            const int col = blk * 16 + (lane & 15);
            _Float16 v = (_Float16)Wd[k * 64 + col];
            fwd[ksblk * 512 + lane * 8 + j] = __builtin_bit_cast(ushort, v);
        }
    }
}

// ---------------------------------------------------------------------------
// Bidirectional LSTM (R13 math, register-diet schedule):
//  - MFMAs split by gate parity: 4 even-b MFMAs -> hf=0 gates -> 4 odd-b
//    MFMAs -> hf=1 gates. Only 4 acc quads live (16 AGPR, was 32).
//  - Awr fragments live in LDS (8 KB/block, conflict-free b128 reads); the
//    base offset is laundered through inline asm each step so the compiler
//    cannot hoist the loop-invariant reads back into 32 VGPRs.
// Gates (prescaled rows: i,f,o by -L2E, g by +2*L2E):
//   cn = [c*D2 + (Eg-1)*D1] * rcp(D1*D2),  D1=1+Ef, D2=(1+Ei)(1+Eg)
//   h  = (Ec-1) * rcp((1+Eo)(1+Ec)),       Ec = exp2(2*L2E*cn)
// ---------------------------------------------------------------------------
__global__ __launch_bounds__(256, 4) void lstm_mfma(const int* __restrict__ x,
                                                    const ushort* __restrict__ fwr,
                                                    const ushort* __restrict__ zxt16,
                                                    ushort* __restrict__ state16) {
    __shared__ int toks[16 * 32];                // [t][seq-in-block]
    __shared__ half8_t awr_lds[8 * 64];          // [b][lane] A-fragments, 8 KB

    const int tid = threadIdx.x, lane = tid & 63, wid = tid >> 6;
    const int i15 = lane & 15, grp = lane >> 4;
    const long blkSeq = (long)blockIdx.x * 32;

    if (tid < 128) {   // stage 32 seqs x 16 tokens, transposed
        int s = tid >> 2, t4 = (tid & 3) * 4;
        int4 v = *(const int4*)(x + (blkSeq + s) * 16 + t4);
        toks[(t4 + 0) * 32 + s] = v.x; toks[(t4 + 1) * 32 + s] = v.y;
        toks[(t4 + 2) * 32 + s] = v.z; toks[(t4 + 3) * 32 + s] = v.w;
    }
    {   // stage Awr fragments into LDS (512 half8 entries)
        const half8_t* fwr8 = (const half8_t*)fwr;
        awr_lds[tid]       = fwr8[tid];
        awr_lds[tid + 256] = fwr8[tid + 256];
    }
    __syncthreads();

    const int seqIB = wid * 8 + (i15 & 7);       // this lane's column's sequence
    const bool bw = i15 >= 8;                    // cols 8-15 run backward
    const int dstep = bw ? -32 : 32;
    int idx = (bw ? 15 * 32 : 0) + seqIB;

    float creg[4][2];                            // c for unit hf*16+4grp+r
    #pragma unroll
    for (int r = 0; r < 4; ++r) creg[r][0] = creg[r][1] = 0.f;
    half8_t Bh = __builtin_bit_cast(half8_t, (u32x4_t){0u, 0u, 0u, 0u});

    // token pipeline (1 ahead) + zx double buffer (1 ahead)
    int tok_cur = toks[idx]; idx += dstep;
    int tok_nx  = toks[idx]; idx += dstep;
    const half8_t* ztab = (const half8_t*)zxt16;  // 16B units
    half8_t zb0[4], zb1[4];
    {
        const half8_t* zr = ztab + (long)tok_cur * 16 + grp * 4;
        #pragma unroll
        for (int c = 0; c < 4; ++c) zb0[c] = zr[c];
    }

    unsigned awr_off = 0;                        // laundered each step

    #pragma unroll 2
    for (int s = 0; s < 16; ++s) {
        asm volatile("" : "+v"(awr_off));        // make LDS base opaque
        const half8_t* Aw = (const half8_t*)((const char*)awr_lds + awr_off) + lane;
        const half8_t* zc = (s & 1) ? zb1 : zb0;
        const bool m = (tok_cur != 0);
        u32x4_t w;

        // (A) even b-blocks (hf=0 rows): acc = s_row*(z_x + Wr^T @ h^T)
        f32x4_t acce[4];
        #pragma unroll
        for (int k = 0; k < 4; ++k) {
            f32x4_t cc = { (float)zc[k][0], (float)zc[k][1],
                           (float)zc[k][2], (float)zc[k][3] };
            acce[k] = __builtin_amdgcn_mfma_f32_16x16x32_f16(Aw[(2 * k) * 64], Bh, cc, 0, 0, 0);
        }
        // (B) prefetch zx(s+1) into the other parity buffer (issue early)
        if (s < 15) {
            const half8_t* zr = ztab + (long)tok_nx * 16 + grp * 4;
            if (s & 1) {
                #pragma unroll
                for (int c = 0; c < 4; ++c) zb0[c] = zr[c];
            } else {
                #pragma unroll
                for (int c = 0; c < 4; ++c) zb1[c] = zr[c];
            }
        }
        // (C) gates hf=0 (acce = i,f,g,o rows for units 4grp+r)
        {
            float hn[4];
            #pragma unroll
            for (int r = 0; r < 4; ++r) {
                float Ei = __builtin_amdgcn_exp2f(acce[0][r]);
                float Ef = __builtin_amdgcn_exp2f(acce[1][r]);
                float Eg = __builtin_amdgcn_exp2f(acce[2][r]);
                float Eo = __builtin_amdgcn_exp2f(acce[3][r]);
                float D1 = 1.f + Ef;
                float D2 = (1.f + Ei) * (1.f + Eg);
                float num = fmaf(creg[r][0], D2, (Eg - 1.f) * D1);
                float cn  = num * __builtin_amdgcn_rcpf(D1 * D2);
                float Ec  = __builtin_amdgcn_exp2f(cn * (2.f * L2E));
                float roc = __builtin_amdgcn_rcpf((1.f + Eo) * (1.f + Ec));
                hn[r] = (Ec - 1.f) * roc;
                creg[r][0] = m ? cn : creg[r][0];
            }
            fp16x2_t pa = __builtin_amdgcn_cvt_pkrtz(hn[0], hn[1]);
            fp16x2_t pb = __builtin_amdgcn_cvt_pkrtz(hn[2], hn[3]);
            w.x = __builtin_bit_cast(unsigned int, pa);
            w.y = __builtin_bit_cast(unsigned int, pb);
        }
        // (D) odd b-blocks (hf=1 rows); Bh still holds previous h
        f32x4_t acco[4];
        #pragma unroll
        for (int k = 0; k < 4; ++k) {
            f32x4_t cc = { (float)zc[k][4], (float)zc[k][5],
                           (float)zc[k][6], (float)zc[k][7] };
            acco[k] = __builtin_amdgcn_mfma_f32_16x16x32_f16(Aw[(2 * k + 1) * 64], Bh, cc, 0, 0, 0);
        }
        // (E) gates hf=1
        {
            float hn[4];
            #pragma unroll
            for (int r = 0; r < 4; ++r) {
                float Ei = __builtin_amdgcn_exp2f(acco[0][r]);
                float Ef = __builtin_amdgcn_exp2f(acco[1][r]);
                float Eg = __builtin_amdgcn_exp2f(acco[2][r]);
                float Eo = __builtin_amdgcn_exp2f(acco[3][r]);
                float D1 = 1.f + Ef;
                float D2 = (1.f + Ei) * (1.f + Eg);
                float num = fmaf(creg[r][1], D2, (Eg - 1.f) * D1);
                float cn  = num * __builtin_amdgcn_rcpf(D1 * D2);
                float Ec  = __builtin_amdgcn_exp2f(cn * (2.f * L2E));
                float roc = __builtin_amdgcn_rcpf((1.f + Eo) * (1.f + Ec));
                hn[r] = (Ec - 1.f) * roc;
                creg[r][1] = m ? cn : creg[r][1];
            }
            fp16x2_t pa = __builtin_amdgcn_cvt_pkrtz(hn[0], hn[1]);
            fp16x2_t pb = __builtin_amdgcn_cvt_pkrtz(hn[2], hn[3]);
            w.z = __builtin_bit_cast(unsigned int, pa);
            w.w = __builtin_bit_cast(unsigned int, pb);
        }
        half8_t Bh_new = __builtin_bit_cast(half8_t, w);
        Bh = m ? Bh_new : Bh;                    // packed select
        // advance token pipeline
        tok_cur = tok_nx;
        if (s < 14) { tok_nx = toks[idx]; idx += dstep; }
    }

    // epilogue: Bh words 0,1 = units 4grp..4grp+3 ; words 2,3 = 16+4grp..+3
    {
        u32x4_t wv = __builtin_bit_cast(u32x4_t, Bh);
        ushort* base = state16 + (blkSeq + seqIB) * 64 + (bw ? 32 : 0);
        uint2 lo = {wv.x, wv.y}, hi = {wv.z, wv.w};
        *(uint2*)(base + 4 * grp) = lo;
        *(uint2*)(base + 16 + 4 * grp) = hi;
    }
}

// ---------------------------------------------------------------------------
// Projection GEMM (R12/R13-proven, verbatim): 4 waves/block, wave = one
// 16-col N-block, no LDS/reduce. out = tanh(state16 @ Wd + bd).
// ---------------------------------------------------------------------------
__global__ __launch_bounds__(256) void proj_mfma(const ushort* __restrict__ state16,
                                                 const ushort* __restrict__ fwd,
                                                 const float* __restrict__ bd,
                                                 float* __restrict__ out) {
    const int tid = threadIdx.x, lane = tid & 63, wid = tid >> 6;
    const int i15 = lane & 15, grp = lane >> 4;
    const int r0 = blockIdx.x * 16;

    const half8_t* fw8 = (const half8_t*)fwd;
    const half8_t* sa  = (const half8_t*)state16;

    float cinit = bd[wid * 16 + i15];
    f32x4_t acc = {cinit, cinit, cinit, cinit};

    const int abase = (r0 + i15) * 512 + grp;   // half8 index into state16
    #pragma unroll 4
    for (int ks = 0; ks < 128; ++ks) {
        half8_t A = sa[abase + ks * 4];
        acc = __builtin_amdgcn_mfma_f32_16x16x32_f16(A, fw8[(ks * 4 + wid) * 64 + lane],
                                                     acc, 0, 0, 0);
    }

    #pragma unroll
    for (int q = 0; q < 4; ++q) {
        float e = __builtin_amdgcn_exp2f(acc[q] * (2.f * L2E));
        float t = fmaf(-2.f, __builtin_amdgcn_rcpf(1.f + e), 1.f);
        out[(r0 + grp * 4 + q) * 64 + wid * 16 + i15] = t;
    }
}

extern "C" void kernel_launch(void* const* d_in, const int* in_sizes, int n_in,
                              void* d_out, int out_size, void* d_ws, size_t ws_size,
                              hipStream_t stream) {
    const int*   x    = (const int*)d_in[0];
    const float* emb  = (const float*)d_in[1];
    const float* Wk   = (const float*)d_in[2];
    const float* Wr   = (const float*)d_in[3];
    const float* bias = (const float*)d_in[4];
    const float* Wd   = (const float*)d_in[5];
    const float* bd   = (const float*)d_in[6];
    float* out = (float*)d_out;

    ushort* state16 = (ushort*)d_ws;                          // 16,777,216 B
    ushort* zxt16   = (ushort*)((char*)d_ws + 16777216);      //  2,560,000 B
    ushort* fwr     = (ushort*)((char*)d_ws + 19337216);      //      8,192 B
    ushort* fwd     = (ushort*)((char*)d_ws + 19345408);      //    524,288 B

    prep_all<<<5136, 256, 0, stream>>>(emb, Wr, Wk, Wd, bias, zxt16, fwr, fwd);
    lstm_mfma<<<NSEQ / 32, 256, 0, stream>>>(x, fwr, zxt16, state16);
    proj_mfma<<<BATCH / 16, 256, 0, stream>>>(state16, fwd, bd, out);
}